// Round 1
// 972.295 us; speedup vs baseline: 1.6017x; 1.6017x over previous
//
#include <hip/hip_runtime.h>

// FNO forward. Round 4: entire spectral pipeline moved to f16 MFMA GEMMs.
//  - k_fwd1: row-DFT as GEMM  t1T[ch][n'][h] = V[row][w] * B1t[n'][w]^T   (f16 out)
//  - k_fwd2: col-DFT as GEMM  D2 = A2[m'][h] * t1T[ch]^T, complex combine -> cbuf
//            (full K=512 per block: no atomics, no memset)
//  - k_inv1: inv col-DFT as GEMM with swapped roles: e[ch][h][nn] = B3t(c2) * A3^T
//  - k_inv2: inv row-DFT as GEMM: s[row][w] = B4T[w][k] * E[row][k]^T     (f16 out)
//  - s, t1, e stored f16 (halved traffic); k_conv reads f16 s directly.
//  - k_mix unchanged (memory-bound on A, reads A exactly once).
// MFMA frag convention (verified by k_conv): A lane holds A[l&15][(l>>4)*8+j],
// B lane holds B[(l>>4)*8+j][l&15], D lane holds D[(l>>4)*4+r][l&15].
// LDS row strides 72 (BK=64) / 136 (K=128) f16: 16B-aligned, 2-way banks (free).

constexpr int Hn = 512, Wn = 512, Cn = 64, Mn = 64, Ln = 4;
constexpr int HWn = Hn * Wn;

typedef _Float16 half8 __attribute__((ext_vector_type(8)));
typedef float f32x4 __attribute__((ext_vector_type(4)));

__device__ __forceinline__ float gelu_f(float x) {
  // jax.nn.gelu approximate=True
  float t = 0.7978845608028654f * (x + 0.044715f * x * x * x);
  float e = __expf(2.0f * t);
  float th = 1.0f - 2.0f / (e + 1.0f);
  return 0.5f * x * (1.0f + th);
}

// ---- f16 DFT twiddle matrices (one-time, 4 x 128 KB) ----
// B1t[n'][w]  n'<64: cos(2pi n w/512)        n'>=64: -sin(2pi n w/512)
// A2 [m'][h]  m'<64: cos(2pi(m-32)h/512)     m'>=64: -sin(...)
// A3 [h][k]   k<64 : cos(2pi(k-32)h/512)     k>=64 : +sin(...)
// B4T[w][k]   k<64 : a_k cos(2pi k w/512)    k>=64 : -a_k sin(...)   a_0=1 else 2
__global__ __launch_bounds__(256) void k_init_tw(_Float16* __restrict__ B1t,
                                                 _Float16* __restrict__ A2t,
                                                 _Float16* __restrict__ A3t,
                                                 _Float16* __restrict__ B4t) {
  int j = blockIdx.x * 256 + threadIdx.x;  // 0..65535
  const float TPI = 6.283185307179586f / 512.0f;
  {
    int n = j >> 9, w = j & 511;
    int idx = ((n & 63) * w) & 511;
    float ang = TPI * (float)idx;
    B1t[j] = (_Float16)((n < 64) ? cosf(ang) : -sinf(ang));
  }
  {
    int mp = j >> 9, h = j & 511;
    int idx = (((mp & 63) - 32) * h) & 511;
    float ang = TPI * (float)idx;
    A2t[j] = (_Float16)((mp < 64) ? cosf(ang) : -sinf(ang));
  }
  {
    int h = j >> 7, k = j & 127;
    int idx = (((k & 63) - 32) * h) & 511;
    float ang = TPI * (float)idx;
    A3t[j] = (_Float16)((k < 64) ? cosf(ang) : sinf(ang));
  }
  {
    int w = j >> 7, k = j & 127;
    int kk = k & 63;
    int idx = (kk * w) & 511;
    float ang = TPI * (float)idx;
    float al = (kk == 0) ? 1.0f : 2.0f;
    B4t[j] = (_Float16)((k < 64) ? al * cosf(ang) : -al * sinf(ang));
  }
}

__global__ __launch_bounds__(256) void k_encode(const float* __restrict__ u,
                                                const float* __restrict__ x,
                                                const float* __restrict__ ew,
                                                const float* __restrict__ eb,
                                                float* __restrict__ v) {
  __shared__ float w[Cn][3];
  __shared__ float b[Cn];
  int tid = threadIdx.x;
  if (tid < Cn) {
    w[tid][0] = ew[tid * 3 + 0];
    w[tid][1] = ew[tid * 3 + 1];
    w[tid][2] = ew[tid * 3 + 2];
    b[tid] = eb[tid];
  }
  __syncthreads();
  int p = blockIdx.x * 256 + tid;
  float x0 = x[p], x1 = x[HWn + p], uu = u[p];
  #pragma unroll 8
  for (int c = 0; c < Cn; c++)
    v[c * HWn + p] = fmaf(w[c][0], x0, fmaf(w[c][1], x1, fmaf(w[c][2], uu, b[c])));
}

// ---- row DFT: t1T[ch][n'][h] (f16), n'<64 = Re, n'>=64 = Im ----
// GEMM per block: M=64 pixel-rows, N=128, K=512 (BK=64, 8 chunks).
__global__ __launch_bounds__(256) void k_fwd1(const float* __restrict__ v,
                                              const _Float16* __restrict__ B1t,
                                              _Float16* __restrict__ t1) {
  __shared__ _Float16 Vh[64 * 72];    // A: v rows (f32->f16)
  __shared__ _Float16 Bs[128 * 72];   // Bt: B1t rows [n'][w-chunk]
  int tid = threadIdx.x;
  int wv = tid >> 6, lane = tid & 63;
  int col = lane & 15, quad = lane >> 4;
  int pb = blockIdx.x * 64;           // pixel-row base (= ch*512 + h)

  f32x4 acc[8];
  #pragma unroll
  for (int nt = 0; nt < 8; nt++) acc[nt] = (f32x4){0.f, 0.f, 0.f, 0.f};

  for (int kc = 0; kc < 8; kc++) {
    __syncthreads();
    #pragma unroll
    for (int i = 0; i < 4; i++) {     // 64 rows x 16 float4
      int f = tid + 256 * i;
      int r_ = f >> 4, c4 = f & 15;
      float4 val = *(const float4*)&v[(size_t)(pb + r_) * Wn + kc * 64 + c4 * 4];
      union { _Float16 h4[4]; uint2 u; } pk;
      pk.h4[0] = (_Float16)val.x; pk.h4[1] = (_Float16)val.y;
      pk.h4[2] = (_Float16)val.z; pk.h4[3] = (_Float16)val.w;
      *(uint2*)&Vh[r_ * 72 + c4 * 4] = pk.u;
    }
    #pragma unroll
    for (int i = 0; i < 4; i++) {     // 128 rows x 8 half8
      int f = tid + 256 * i;
      int r_ = f >> 3, c8 = f & 7;
      *(half8*)&Bs[r_ * 72 + c8 * 8] =
          *(const half8*)&B1t[r_ * 512 + kc * 64 + c8 * 8];
    }
    __syncthreads();
    #pragma unroll
    for (int kh = 0; kh < 2; kh++) {
      half8 a0 = *(const half8*)&Vh[(16 * wv + col) * 72 + kh * 32 + quad * 8];
      #pragma unroll
      for (int nt = 0; nt < 8; nt++) {
        half8 b = *(const half8*)&Bs[(nt * 16 + col) * 72 + kh * 32 + quad * 8];
        acc[nt] = __builtin_amdgcn_mfma_f32_16x16x32_f16(a0, b, acc[nt], 0, 0, 0);
      }
    }
  }
  // D[row][n'] -> t1T[ch][n'][h]: 4 consecutive h per lane = packed 8B store
  int mrow = 16 * wv + quad * 4;
  int grow = pb + mrow;
  int ch = grow >> 9, h0 = grow & 511;
  #pragma unroll
  for (int nt = 0; nt < 8; nt++) {
    int ncol = nt * 16 + col;
    union { _Float16 h4[4]; uint2 u; } pk;
    #pragma unroll
    for (int r = 0; r < 4; r++) pk.h4[r] = (_Float16)acc[nt][r];
    *(uint2*)&t1[((size_t)ch * 128 + ncol) * 512 + h0] = pk.u;
  }
}

// ---- col DFT: cbuf[ch][m][n] (float2) = (1/HW) * complex combine of
// D2[128 m'][128 col] = A2 * T1, K=512. One block per channel. ----
__global__ __launch_bounds__(256) void k_fwd2(const _Float16* __restrict__ t1,
                                              const _Float16* __restrict__ A2t,
                                              float2* __restrict__ cb) {
  __shared__ _Float16 Ash[128 * 72];
  __shared__ _Float16 Bsh[128 * 72];
  int tid = threadIdx.x;
  int wv = tid >> 6, lane = tid & 63;
  int col = lane & 15, quad = lane >> 4;
  int ch = blockIdx.x;

  f32x4 acc[2][8];
  #pragma unroll
  for (int mt = 0; mt < 2; mt++)
    #pragma unroll
    for (int nt = 0; nt < 8; nt++) acc[mt][nt] = (f32x4){0.f, 0.f, 0.f, 0.f};

  for (int kc = 0; kc < 8; kc++) {
    __syncthreads();
    #pragma unroll
    for (int i = 0; i < 4; i++) {
      int f = tid + 256 * i;
      int r_ = f >> 3, c8 = f & 7;
      *(half8*)&Ash[r_ * 72 + c8 * 8] =
          *(const half8*)&A2t[r_ * 512 + kc * 64 + c8 * 8];
      *(half8*)&Bsh[r_ * 72 + c8 * 8] =
          *(const half8*)&t1[((size_t)ch * 128 + r_) * 512 + kc * 64 + c8 * 8];
    }
    __syncthreads();
    #pragma unroll
    for (int kh = 0; kh < 2; kh++) {
      half8 a0 = *(const half8*)&Ash[(16 * wv + col) * 72 + kh * 32 + quad * 8];
      half8 a1 = *(const half8*)&Ash[(64 + 16 * wv + col) * 72 + kh * 32 + quad * 8];
      #pragma unroll
      for (int nt = 0; nt < 8; nt++) {
        half8 b = *(const half8*)&Bsh[(nt * 16 + col) * 72 + kh * 32 + quad * 8];
        acc[0][nt] = __builtin_amdgcn_mfma_f32_16x16x32_f16(a0, b, acc[0][nt], 0, 0, 0);
        acc[1][nt] = __builtin_amdgcn_mfma_f32_16x16x32_f16(a1, b, acc[1][nt], 0, 0, 0);
      }
    }
  }
  // c_r = D[m][n] - D[64+m][64+n]; c_i = D[m][64+n] + D[64+m][n]
  const float sc = 1.0f / 262144.0f;
  #pragma unroll
  for (int nt = 0; nt < 4; nt++) {
    #pragma unroll
    for (int r = 0; r < 4; r++) {
      int m = 16 * wv + quad * 4 + r;
      int n = 16 * nt + col;
      float cr = (acc[0][nt][r] - acc[1][nt + 4][r]) * sc;
      float ci = (acc[0][nt + 4][r] + acc[1][nt][r]) * sc;
      cb[((size_t)ch * 64 + m) * 64 + n] = make_float2(cr, ci);
    }
  }
}

// c2[o,m,n] = sum_i A[o,i,m,n] * c[i,m,n]  (complex). Memory-bound on A.
__global__ __launch_bounds__(256) void k_mix(const float* __restrict__ Ar,
                                             const float* __restrict__ Ai,
                                             const float2* __restrict__ cb,
                                             float2* __restrict__ c2b) {
  __shared__ float2 csh[64][65];
  int tid = threadIdx.x;
  int m = blockIdx.x, og = blockIdx.y;
  for (int j = tid; j < 4096; j += 256) {
    int i = j >> 6, n = j & 63;
    csh[i][n] = cb[(i * 64 + m) * 64 + n];
  }
  __syncthreads();
  int o = og * 4 + (tid >> 6);
  int n = tid & 63;
  const float* ar = Ar + (size_t)o * 64 * 4096 + m * 64 + n;
  const float* ai = Ai + (size_t)o * 64 * 4096 + m * 64 + n;
  float accr = 0.f, acci = 0.f;
  #pragma unroll 8
  for (int i = 0; i < 64; i++) {
    float a_r = ar[i * 4096];
    float a_i = ai[i * 4096];
    float2 cv = csh[i][n];
    accr = fmaf(a_r, cv.x, fmaf(-a_i, cv.y, accr));
    acci = fmaf(a_r, cv.y, fmaf(a_i, cv.x, acci));
  }
  c2b[(o * 64 + m) * 64 + n] = make_float2(accr, acci);
}

// ---- inv col DFT: e[ch][h][nn] (f16), nn<64 = Re, nn>=64 = Im ----
// Swapped roles: D[nn][h] = B3t(c2) [nn][k] x A3[h][k]^T, K=128.
__global__ __launch_bounds__(256) void k_inv1(const float2* __restrict__ c2,
                                              const _Float16* __restrict__ A3t,
                                              _Float16* __restrict__ e) {
  __shared__ _Float16 Csh[128 * 136];  // A: B3t from cmix
  __shared__ _Float16 Hsh[128 * 136];  // Bt: A3 rows [h][k]
  int tid = threadIdx.x;
  int ch = blockIdx.x, hb = blockIdx.y;
  for (int j = tid; j < 4096; j += 256) {
    int m = j >> 6, n = j & 63;
    float2 cv = c2[(size_t)ch * 4096 + j];
    Csh[n * 136 + m]              = (_Float16)cv.x;
    Csh[(64 + n) * 136 + 64 + m]  = (_Float16)cv.x;
    Csh[(64 + n) * 136 + m]       = (_Float16)cv.y;
    Csh[n * 136 + 64 + m]         = (_Float16)(-cv.y);
  }
  #pragma unroll
  for (int i = 0; i < 8; i++) {
    int f = tid + 256 * i;
    int r_ = f >> 4, c8 = f & 15;
    *(half8*)&Hsh[r_ * 136 + c8 * 8] =
        *(const half8*)&A3t[(size_t)(hb * 128 + r_) * 128 + c8 * 8];
  }
  __syncthreads();
  int wv = tid >> 6, lane = tid & 63;
  int col = lane & 15, quad = lane >> 4;
  f32x4 acc[2][8];
  #pragma unroll
  for (int mt = 0; mt < 2; mt++)
    #pragma unroll
    for (int nt = 0; nt < 8; nt++) acc[mt][nt] = (f32x4){0.f, 0.f, 0.f, 0.f};
  #pragma unroll
  for (int ks = 0; ks < 4; ks++) {
    half8 a0 = *(const half8*)&Csh[(32 * wv + col) * 136 + ks * 32 + quad * 8];
    half8 a1 = *(const half8*)&Csh[(32 * wv + 16 + col) * 136 + ks * 32 + quad * 8];
    #pragma unroll
    for (int nt = 0; nt < 8; nt++) {
      half8 b = *(const half8*)&Hsh[(16 * nt + col) * 136 + ks * 32 + quad * 8];
      acc[0][nt] = __builtin_amdgcn_mfma_f32_16x16x32_f16(a0, b, acc[0][nt], 0, 0, 0);
      acc[1][nt] = __builtin_amdgcn_mfma_f32_16x16x32_f16(a1, b, acc[1][nt], 0, 0, 0);
    }
  }
  // D[nn][h]: 4 consecutive nn per lane -> packed 8B at e[ch][h][nn0]
  #pragma unroll
  for (int mt = 0; mt < 2; mt++) {
    int nn0 = 32 * wv + 16 * mt + quad * 4;
    #pragma unroll
    for (int nt = 0; nt < 8; nt++) {
      int h = hb * 128 + 16 * nt + col;
      union { _Float16 h4[4]; uint2 u; } pk;
      #pragma unroll
      for (int r = 0; r < 4; r++) pk.h4[r] = (_Float16)acc[mt][nt][r];
      *(uint2*)&e[((size_t)ch * 512 + h) * 128 + nn0] = pk.u;
    }
  }
}

// ---- inv row DFT: s[row][w] (f16) = B4T[w][k] x E[row][k]^T, K=128 ----
__global__ __launch_bounds__(256) void k_inv2(const _Float16* __restrict__ e,
                                              const _Float16* __restrict__ B4t,
                                              _Float16* __restrict__ s) {
  __shared__ _Float16 Wsh[128 * 136];  // A: B4T rows [w][k]
  __shared__ _Float16 Esh[128 * 136];  // Bt: E rows [pixel-row][k]
  int tid = threadIdx.x;
  int pb = blockIdx.x * 128;           // pixel-row base
  int wb = blockIdx.y;                 // w block
  #pragma unroll
  for (int i = 0; i < 8; i++) {
    int f = tid + 256 * i;
    int r_ = f >> 4, c8 = f & 15;
    *(half8*)&Wsh[r_ * 136 + c8 * 8] =
        *(const half8*)&B4t[(size_t)(wb * 128 + r_) * 128 + c8 * 8];
    *(half8*)&Esh[r_ * 136 + c8 * 8] =
        *(const half8*)&e[(size_t)(pb + r_) * 128 + c8 * 8];
  }
  __syncthreads();
  int wv = tid >> 6, lane = tid & 63;
  int col = lane & 15, quad = lane >> 4;
  f32x4 acc[2][8];
  #pragma unroll
  for (int mt = 0; mt < 2; mt++)
    #pragma unroll
    for (int nt = 0; nt < 8; nt++) acc[mt][nt] = (f32x4){0.f, 0.f, 0.f, 0.f};
  #pragma unroll
  for (int ks = 0; ks < 4; ks++) {
    half8 a0 = *(const half8*)&Wsh[(32 * wv + col) * 136 + ks * 32 + quad * 8];
    half8 a1 = *(const half8*)&Wsh[(32 * wv + 16 + col) * 136 + ks * 32 + quad * 8];
    #pragma unroll
    for (int nt = 0; nt < 8; nt++) {
      half8 b = *(const half8*)&Esh[(16 * nt + col) * 136 + ks * 32 + quad * 8];
      acc[0][nt] = __builtin_amdgcn_mfma_f32_16x16x32_f16(a0, b, acc[0][nt], 0, 0, 0);
      acc[1][nt] = __builtin_amdgcn_mfma_f32_16x16x32_f16(a1, b, acc[1][nt], 0, 0, 0);
    }
  }
  // D[w][row]: 4 consecutive w per lane -> packed 8B at s[row][w0]
  #pragma unroll
  for (int mt = 0; mt < 2; mt++) {
    int w0 = wb * 128 + 32 * wv + 16 * mt + quad * 4;
    #pragma unroll
    for (int nt = 0; nt < 8; nt++) {
      int prow = pb + 16 * nt + col;
      union { _Float16 h4[4]; uint2 u; } pk;
      #pragma unroll
      for (int r = 0; r < 4; r++) pk.h4[r] = (_Float16)acc[mt][nt][r];
      *(uint2*)&s[(size_t)prow * 512 + w0] = pk.u;
    }
  }
}

// v[:,p] += gelu(W2 @ gelu(W1 @ s[:,p] + b1) + b2)  -- f16 MFMA, s now f16.
__global__ __launch_bounds__(256) void k_conv(const _Float16* __restrict__ s,
                                              float* __restrict__ v,
                                              const float* __restrict__ w1,
                                              const float* __restrict__ b1,
                                              const float* __restrict__ w2,
                                              const float* __restrict__ b2) {
  __shared__ _Float16 W1h[64 * 72];   // [o][i]
  __shared__ _Float16 W2h[64 * 72];   // [o][i]
  __shared__ _Float16 XpY2[64 * 72];  // Xp[p][i]; reused as Y2h[o][p] stride 66
  __shared__ _Float16 Y1T[64 * 72];   // [p][o]
  __shared__ float B1[64], B2[64];
  int tid = threadIdx.x;
  int pb = blockIdx.x * 64;

  for (int j = tid; j < 4096; j += 256) {
    int a_ = j >> 6, b_ = j & 63;
    W1h[a_ * 72 + b_] = (_Float16)w1[j];
    W2h[a_ * 72 + b_] = (_Float16)w2[j];
    XpY2[b_ * 72 + a_] = s[(size_t)a_ * HWn + pb + b_];  // Xp[p][i]
  }
  if (tid < 64) { B1[tid] = b1[tid]; B2[tid] = b2[tid]; }
  __syncthreads();

  int wv = tid >> 6, lane = tid & 63;
  int col = lane & 15, quad = lane >> 4;
  int prow = 16 * wv + col;

  // ---- GEMM1: D1[o][p] = W1 * X ----
  f32x4 acc1[4];
  #pragma unroll
  for (int ot = 0; ot < 4; ot++) acc1[ot] = (f32x4){0.f, 0.f, 0.f, 0.f};
  half8 bfr[2];
  #pragma unroll
  for (int kh = 0; kh < 2; kh++)
    bfr[kh] = *(const half8*)&XpY2[prow * 72 + kh * 32 + quad * 8];
  #pragma unroll
  for (int ot = 0; ot < 4; ot++) {
    #pragma unroll
    for (int kh = 0; kh < 2; kh++) {
      half8 afr = *(const half8*)&W1h[(ot * 16 + col) * 72 + kh * 32 + quad * 8];
      acc1[ot] = __builtin_amdgcn_mfma_f32_16x16x32_f16(afr, bfr[kh], acc1[ot], 0, 0, 0);
    }
  }
  #pragma unroll
  for (int ot = 0; ot < 4; ot++) {
    int o0 = ot * 16 + quad * 4;
    union { _Float16 h[4]; uint2 u; } pk;
    #pragma unroll
    for (int r = 0; r < 4; r++)
      pk.h[r] = (_Float16)gelu_f(acc1[ot][r] + B1[o0 + r]);
    *(uint2*)&Y1T[prow * 72 + o0] = pk.u;
  }
  __syncthreads();

  // ---- GEMM2: D2[o][p] = W2 * Y1 ----
  f32x4 acc2[4];
  #pragma unroll
  for (int ot = 0; ot < 4; ot++) acc2[ot] = (f32x4){0.f, 0.f, 0.f, 0.f};
  #pragma unroll
  for (int kh = 0; kh < 2; kh++)
    bfr[kh] = *(const half8*)&Y1T[prow * 72 + kh * 32 + quad * 8];
  #pragma unroll
  for (int ot = 0; ot < 4; ot++) {
    #pragma unroll
    for (int kh = 0; kh < 2; kh++) {
      half8 afr = *(const half8*)&W2h[(ot * 16 + col) * 72 + kh * 32 + quad * 8];
      acc2[ot] = __builtin_amdgcn_mfma_f32_16x16x32_f16(afr, bfr[kh], acc2[ot], 0, 0, 0);
    }
  }
  #pragma unroll
  for (int ot = 0; ot < 4; ot++) {
    int o0 = ot * 16 + quad * 4;
    #pragma unroll
    for (int r = 0; r < 4; r++)
      XpY2[(o0 + r) * 66 + prow] = (_Float16)gelu_f(acc2[ot][r] + B2[o0 + r]);
  }
  __syncthreads();

  for (int j = tid; j < 4096; j += 256) {
    int o = j >> 6, p = j & 63;
    v[(size_t)o * HWn + pb + p] += (float)XpY2[o * 66 + p];
  }
}

__global__ __launch_bounds__(256) void k_decode(const float* __restrict__ v,
                                                const float* __restrict__ dw,
                                                const float* __restrict__ db,
                                                float* __restrict__ out) {
  __shared__ float wsm[64];
  int tid = threadIdx.x;
  if (tid < 64) wsm[tid] = dw[tid];
  __syncthreads();
  int p = blockIdx.x * 256 + tid;
  float acc = db[0];
  #pragma unroll
  for (int i = 0; i < 64; i++) acc = fmaf(wsm[i], v[i * HWn + p], acc);
  out[p] = acc;
}

extern "C" void kernel_launch(void* const* d_in, const int* in_sizes, int n_in,
                              void* d_out, int out_size, void* d_ws, size_t ws_size,
                              hipStream_t stream) {
  const float* u     = (const float*)d_in[0];
  const float* x     = (const float*)d_in[1];
  const float* enc_w = (const float*)d_in[2];
  const float* enc_b = (const float*)d_in[3];
  const float* dec_w = (const float*)d_in[4];
  const float* dec_b = (const float*)d_in[5];
  const float* c1w   = (const float*)d_in[6];
  const float* c1b   = (const float*)d_in[7];
  const float* c2w   = (const float*)d_in[8];
  const float* c2b   = (const float*)d_in[9];
  const float* Are   = (const float*)d_in[10];
  const float* Aim   = (const float*)d_in[11];
  float* out = (float*)d_out;
  float* ws = (float*)d_ws;

  _Float16* B1t = (_Float16*)ws;            // [128][512]
  _Float16* A2t = B1t + 65536;              // [128][512]
  _Float16* A3t = A2t + 65536;              // [512][128]
  _Float16* B4t = A3t + 65536;              // [512][128]
  float* v = ws + 131072;                   // [C][H][W] f32
  _Float16* sh = (_Float16*)(v + (size_t)Cn * HWn);       // [C][H][W] f16
  _Float16* t1 = sh + (size_t)Cn * HWn;                   // [C][128][512] f16
  _Float16* e  = t1 + (size_t)Cn * 128 * 512;             // [C][512][128] f16
  float2* cbuf = (float2*)(e + (size_t)Cn * 512 * 128);   // [C][M][M]
  float2* cmix = cbuf + (size_t)Cn * Mn * Mn;             // [C][M][M]

  k_init_tw<<<dim3(256), dim3(256), 0, stream>>>(B1t, A2t, A3t, B4t);
  k_encode<<<dim3(HWn / 256), dim3(256), 0, stream>>>(u, x, enc_w, enc_b, v);

  for (int l = 0; l < Ln; l++) {
    k_fwd1<<<dim3(Cn * Hn / 64), dim3(256), 0, stream>>>(v, B1t, t1);
    k_fwd2<<<dim3(Cn), dim3(256), 0, stream>>>(t1, A2t, cbuf);
    k_mix<<<dim3(Mn, 16), dim3(256), 0, stream>>>(
        Are + (size_t)l * Cn * Cn * Mn * Mn, Aim + (size_t)l * Cn * Cn * Mn * Mn,
        cbuf, cmix);
    k_inv1<<<dim3(Cn, 4), dim3(256), 0, stream>>>(cmix, A3t, e);
    k_inv2<<<dim3(Cn * Hn / 128, 4), dim3(256), 0, stream>>>(e, B4t, sh);
    k_conv<<<dim3(HWn / 64), dim3(256), 0, stream>>>(
        sh, v, c1w + (size_t)l * 4096, c1b + (size_t)l * 64,
        c2w + (size_t)l * 4096, c2b + (size_t)l * 64);
  }

  k_decode<<<dim3(HWn / 256), dim3(256), 0, stream>>>(v, dec_w, dec_b, out);

  (void)in_sizes; (void)n_in; (void)out_size; (void)ws_size;
}

// Round 2
// 970.663 us; speedup vs baseline: 1.6044x; 1.0017x over previous
//
#include <hip/hip_runtime.h>

// FNO forward. Round 5: layer-tail fusion.
//  - k_tail<WRITE_T1> = inv-row-DFT (old k_inv2) + conv MLP (old k_conv) +
//    next layer's row-DFT (old k_fwd1), one block per h row, 8 w-chunks of 64.
//    S and v_new never touch HBM; t1 for the next layer accumulates in regs.
//  - t1 layout now [h][ch][n'] (8B-packed, line-covering stores from per-h blocks).
//  - k_fwd1 (layer 0 only): MFMA roles swapped (A=B1t, B=Vrows) to emit D[n'][row]
//    so stores pack into the new t1 layout.
//  - k_fwd2: unchanged GEMM, but B operand staged via Tc[h][n'] load + LDS transpose.
//  - k_inv1: h-block 128->64 (grid 64x8, 52 KB LDS, 2 blocks/CU).
// MFMA frag convention (HW-verified earlier): A lane holds A[l&15][(l>>4)*8+j],
// B lane holds B[(l>>4)*8+j][l&15], D lane holds D[(l>>4)*4+r][l&15].
// Both A and B load from row-major [dim][K] arrays; LDS rows stride 72/136 f16.

constexpr int Hn = 512, Wn = 512, Cn = 64, Mn = 64, Ln = 4;
constexpr int HWn = Hn * Wn;

typedef _Float16 half8 __attribute__((ext_vector_type(8)));
typedef float f32x4 __attribute__((ext_vector_type(4)));

__device__ __forceinline__ float gelu_f(float x) {
  // jax.nn.gelu approximate=True
  float t = 0.7978845608028654f * (x + 0.044715f * x * x * x);
  float e = __expf(2.0f * t);
  float th = 1.0f - 2.0f / (e + 1.0f);
  return 0.5f * x * (1.0f + th);
}

// ---- f16 DFT twiddle matrices (one-time, 4 x 128 KB) ----
// B1t[n'][w]  n'<64: cos(2pi n w/512)        n'>=64: -sin(2pi n w/512)
// A2 [m'][h]  m'<64: cos(2pi(m-32)h/512)     m'>=64: -sin(...)
// A3 [h][k]   k<64 : cos(2pi(k-32)h/512)     k>=64 : +sin(...)
// B4T[w][k]   k<64 : a_k cos(2pi k w/512)    k>=64 : -a_k sin(...)   a_0=1 else 2
__global__ __launch_bounds__(256) void k_init_tw(_Float16* __restrict__ B1t,
                                                 _Float16* __restrict__ A2t,
                                                 _Float16* __restrict__ A3t,
                                                 _Float16* __restrict__ B4t) {
  int j = blockIdx.x * 256 + threadIdx.x;  // 0..65535
  const float TPI = 6.283185307179586f / 512.0f;
  {
    int n = j >> 9, w = j & 511;
    int idx = ((n & 63) * w) & 511;
    float ang = TPI * (float)idx;
    B1t[j] = (_Float16)((n < 64) ? cosf(ang) : -sinf(ang));
  }
  {
    int mp = j >> 9, h = j & 511;
    int idx = (((mp & 63) - 32) * h) & 511;
    float ang = TPI * (float)idx;
    A2t[j] = (_Float16)((mp < 64) ? cosf(ang) : -sinf(ang));
  }
  {
    int h = j >> 7, k = j & 127;
    int idx = (((k & 63) - 32) * h) & 511;
    float ang = TPI * (float)idx;
    A3t[j] = (_Float16)((k < 64) ? cosf(ang) : sinf(ang));
  }
  {
    int w = j >> 7, k = j & 127;
    int kk = k & 63;
    int idx = (kk * w) & 511;
    float ang = TPI * (float)idx;
    float al = (kk == 0) ? 1.0f : 2.0f;
    B4t[j] = (_Float16)((k < 64) ? al * cosf(ang) : -al * sinf(ang));
  }
}

__global__ __launch_bounds__(256) void k_encode(const float* __restrict__ u,
                                                const float* __restrict__ x,
                                                const float* __restrict__ ew,
                                                const float* __restrict__ eb,
                                                float* __restrict__ v) {
  __shared__ float w[Cn][3];
  __shared__ float b[Cn];
  int tid = threadIdx.x;
  if (tid < Cn) {
    w[tid][0] = ew[tid * 3 + 0];
    w[tid][1] = ew[tid * 3 + 1];
    w[tid][2] = ew[tid * 3 + 2];
    b[tid] = eb[tid];
  }
  __syncthreads();
  int p = blockIdx.x * 256 + tid;
  float x0 = x[p], x1 = x[HWn + p], uu = u[p];
  #pragma unroll 8
  for (int c = 0; c < Cn; c++)
    v[c * HWn + p] = fmaf(w[c][0], x0, fmaf(w[c][1], x1, fmaf(w[c][2], uu, b[c])));
}

// ---- row DFT (layer 0 only): t1[h][ch][n'] (f16), n'<64 = Re, n'>=64 = Im ----
// GEMM per block: M=128 n' (A=B1t), N=64 pixel-rows (B=v rows), K=512 (8x64).
__global__ __launch_bounds__(256) void k_fwd1(const float* __restrict__ v,
                                              const _Float16* __restrict__ B1t,
                                              _Float16* __restrict__ t1) {
  __shared__ _Float16 Ash[128 * 72];  // B1t rows [n'][w-chunk]
  __shared__ _Float16 Vh[64 * 72];    // v rows f16 [prow][w-chunk]
  int tid = threadIdx.x;
  int wv = tid >> 6, lane = tid & 63;
  int col = lane & 15, quad = lane >> 4;
  int pb = blockIdx.x * 64;           // pixel-row base (= ch*512 + h)

  f32x4 acc[2][4];
  #pragma unroll
  for (int mt = 0; mt < 2; mt++)
    #pragma unroll
    for (int nt = 0; nt < 4; nt++) acc[mt][nt] = (f32x4){0.f, 0.f, 0.f, 0.f};

  for (int kc = 0; kc < 8; kc++) {
    __syncthreads();
    #pragma unroll
    for (int i = 0; i < 4; i++) {     // Vh: 64 rows x 16 float4 -> half4
      int f = tid + 256 * i;
      int r_ = f >> 4, c4 = f & 15;
      float4 val = *(const float4*)&v[(size_t)(pb + r_) * Wn + kc * 64 + c4 * 4];
      union { _Float16 h4[4]; uint2 u; } pk;
      pk.h4[0] = (_Float16)val.x; pk.h4[1] = (_Float16)val.y;
      pk.h4[2] = (_Float16)val.z; pk.h4[3] = (_Float16)val.w;
      *(uint2*)&Vh[r_ * 72 + c4 * 4] = pk.u;
    }
    #pragma unroll
    for (int i = 0; i < 4; i++) {     // Ash: 128 rows x 8 half8
      int f = tid + 256 * i;
      int r_ = f >> 3, c8 = f & 7;
      *(half8*)&Ash[r_ * 72 + c8 * 8] =
          *(const half8*)&B1t[(size_t)r_ * 512 + kc * 64 + c8 * 8];
    }
    __syncthreads();
    #pragma unroll
    for (int mt = 0; mt < 2; mt++)
      #pragma unroll
      for (int kh = 0; kh < 2; kh++) {
        half8 af = *(const half8*)&Ash[(32 * wv + 16 * mt + col) * 72 + kh * 32 + quad * 8];
        #pragma unroll
        for (int nt = 0; nt < 4; nt++) {
          half8 bf = *(const half8*)&Vh[(16 * nt + col) * 72 + kh * 32 + quad * 8];
          acc[mt][nt] = __builtin_amdgcn_mfma_f32_16x16x32_f16(af, bf, acc[mt][nt], 0, 0, 0);
        }
      }
  }
  // D[n'][prow] -> t1[h][ch][n'0..3] packed 8B
  #pragma unroll
  for (int mt = 0; mt < 2; mt++) {
    int n0 = 32 * wv + 16 * mt + quad * 4;
    #pragma unroll
    for (int nt = 0; nt < 4; nt++) {
      int prow = pb + 16 * nt + col;
      int ch = prow >> 9, hh = prow & 511;
      union { _Float16 h4[4]; uint2 u; } pk;
      #pragma unroll
      for (int r = 0; r < 4; r++) pk.h4[r] = (_Float16)acc[mt][nt][r];
      *(uint2*)&t1[((size_t)hh * 64 + ch) * 128 + n0] = pk.u;
    }
  }
}

// ---- col DFT: cbuf[ch][m][n] (float2) = (1/HW) * complex combine of
// D2[128 m'][128 col] = A2 * T1ch^T, K=512. One block per channel. ----
__global__ __launch_bounds__(256) void k_fwd2(const _Float16* __restrict__ t1,
                                              const _Float16* __restrict__ A2t,
                                              float2* __restrict__ cb) {
  __shared__ _Float16 Ash[128 * 72];
  __shared__ _Float16 Bsh[128 * 72];
  __shared__ _Float16 Tc[64 * 136];   // t1 chunk [h][n'] before transpose
  int tid = threadIdx.x;
  int wv = tid >> 6, lane = tid & 63;
  int col = lane & 15, quad = lane >> 4;
  int ch = blockIdx.x;

  f32x4 acc[2][8];
  #pragma unroll
  for (int mt = 0; mt < 2; mt++)
    #pragma unroll
    for (int nt = 0; nt < 8; nt++) acc[mt][nt] = (f32x4){0.f, 0.f, 0.f, 0.f};

  for (int kc = 0; kc < 8; kc++) {
    __syncthreads();
    #pragma unroll
    for (int i = 0; i < 4; i++) {
      int f = tid + 256 * i;
      {
        int r_ = f >> 3, c8 = f & 7;
        *(half8*)&Ash[r_ * 72 + c8 * 8] =
            *(const half8*)&A2t[r_ * 512 + kc * 64 + c8 * 8];
      }
      {
        int r_ = f >> 4, c8 = f & 15;   // Tc[hrel][n'] <- t1[h][ch][n']
        *(half8*)&Tc[r_ * 136 + c8 * 8] =
            *(const half8*)&t1[((size_t)(kc * 64 + r_) * 64 + ch) * 128 + c8 * 8];
      }
    }
    __syncthreads();
    // transpose Tc[h][n'] -> Bsh[n'][h]
    #pragma unroll 8
    for (int i = 0; i < 32; i++) {
      int f = tid + 256 * i;
      int hh = f & 63, nn = f >> 6;
      Bsh[nn * 72 + hh] = Tc[hh * 136 + nn];
    }
    __syncthreads();
    #pragma unroll
    for (int kh = 0; kh < 2; kh++) {
      half8 a0 = *(const half8*)&Ash[(16 * wv + col) * 72 + kh * 32 + quad * 8];
      half8 a1 = *(const half8*)&Ash[(64 + 16 * wv + col) * 72 + kh * 32 + quad * 8];
      #pragma unroll
      for (int nt = 0; nt < 8; nt++) {
        half8 b = *(const half8*)&Bsh[(nt * 16 + col) * 72 + kh * 32 + quad * 8];
        acc[0][nt] = __builtin_amdgcn_mfma_f32_16x16x32_f16(a0, b, acc[0][nt], 0, 0, 0);
        acc[1][nt] = __builtin_amdgcn_mfma_f32_16x16x32_f16(a1, b, acc[1][nt], 0, 0, 0);
      }
    }
  }
  // c_r = D[m][n] - D[64+m][64+n]; c_i = D[m][64+n] + D[64+m][n]
  const float sc = 1.0f / 262144.0f;
  #pragma unroll
  for (int nt = 0; nt < 4; nt++) {
    #pragma unroll
    for (int r = 0; r < 4; r++) {
      int m = 16 * wv + quad * 4 + r;
      int n = 16 * nt + col;
      float cr = (acc[0][nt][r] - acc[1][nt + 4][r]) * sc;
      float ci = (acc[0][nt + 4][r] + acc[1][nt][r]) * sc;
      cb[((size_t)ch * 64 + m) * 64 + n] = make_float2(cr, ci);
    }
  }
}

// c2[o,m,n] = sum_i A[o,i,m,n] * c[i,m,n]  (complex). Memory-bound on A.
__global__ __launch_bounds__(256) void k_mix(const float* __restrict__ Ar,
                                             const float* __restrict__ Ai,
                                             const float2* __restrict__ cb,
                                             float2* __restrict__ c2b) {
  __shared__ float2 csh[64][65];
  int tid = threadIdx.x;
  int m = blockIdx.x, og = blockIdx.y;
  for (int j = tid; j < 4096; j += 256) {
    int i = j >> 6, n = j & 63;
    csh[i][n] = cb[(i * 64 + m) * 64 + n];
  }
  __syncthreads();
  int o = og * 4 + (tid >> 6);
  int n = tid & 63;
  const float* ar = Ar + (size_t)o * 64 * 4096 + m * 64 + n;
  const float* ai = Ai + (size_t)o * 64 * 4096 + m * 64 + n;
  float accr = 0.f, acci = 0.f;
  #pragma unroll 8
  for (int i = 0; i < 64; i++) {
    float a_r = ar[i * 4096];
    float a_i = ai[i * 4096];
    float2 cv = csh[i][n];
    accr = fmaf(a_r, cv.x, fmaf(-a_i, cv.y, accr));
    acci = fmaf(a_r, cv.y, fmaf(a_i, cv.x, acci));
  }
  c2b[(o * 64 + m) * 64 + n] = make_float2(accr, acci);
}

// ---- inv col DFT: e[ch][h][nn] (f16), nn<64 = Re, nn>=64 = Im ----
// D[nn 128][h 64] = B3t(c2)[nn][k] x A3[h][k]^T, K=128. Grid (64 ch, 8 hb).
__global__ __launch_bounds__(256) void k_inv1(const float2* __restrict__ c2,
                                              const _Float16* __restrict__ A3t,
                                              _Float16* __restrict__ e) {
  __shared__ _Float16 Csh[128 * 136];  // complex-expanded c2: [nn][k]
  __shared__ _Float16 Hsh[64 * 136];   // A3 rows [h][k]
  int tid = threadIdx.x;
  int ch = blockIdx.x, hb = blockIdx.y;
  for (int j = tid; j < 4096; j += 256) {
    int m = j >> 6, n = j & 63;
    float2 cv = c2[(size_t)ch * 4096 + j];
    Csh[n * 136 + m]              = (_Float16)cv.x;
    Csh[(64 + n) * 136 + 64 + m]  = (_Float16)cv.x;
    Csh[(64 + n) * 136 + m]       = (_Float16)cv.y;
    Csh[n * 136 + 64 + m]         = (_Float16)(-cv.y);
  }
  #pragma unroll
  for (int i = 0; i < 4; i++) {
    int f = tid + 256 * i;
    int r_ = f >> 4, c8 = f & 15;
    *(half8*)&Hsh[r_ * 136 + c8 * 8] =
        *(const half8*)&A3t[(size_t)(hb * 64 + r_) * 128 + c8 * 8];
  }
  __syncthreads();
  int wv = tid >> 6, lane = tid & 63;
  int col = lane & 15, quad = lane >> 4;
  f32x4 acc[2][4];
  #pragma unroll
  for (int mt = 0; mt < 2; mt++)
    #pragma unroll
    for (int nt = 0; nt < 4; nt++) acc[mt][nt] = (f32x4){0.f, 0.f, 0.f, 0.f};
  #pragma unroll
  for (int ks = 0; ks < 4; ks++) {
    half8 a0 = *(const half8*)&Csh[(32 * wv + col) * 136 + ks * 32 + quad * 8];
    half8 a1 = *(const half8*)&Csh[(32 * wv + 16 + col) * 136 + ks * 32 + quad * 8];
    #pragma unroll
    for (int nt = 0; nt < 4; nt++) {
      half8 b = *(const half8*)&Hsh[(16 * nt + col) * 136 + ks * 32 + quad * 8];
      acc[0][nt] = __builtin_amdgcn_mfma_f32_16x16x32_f16(a0, b, acc[0][nt], 0, 0, 0);
      acc[1][nt] = __builtin_amdgcn_mfma_f32_16x16x32_f16(a1, b, acc[1][nt], 0, 0, 0);
    }
  }
  #pragma unroll
  for (int mt = 0; mt < 2; mt++) {
    int nn0 = 32 * wv + 16 * mt + quad * 4;
    #pragma unroll
    for (int nt = 0; nt < 4; nt++) {
      int h = hb * 64 + 16 * nt + col;
      union { _Float16 h4[4]; uint2 u; } pk;
      #pragma unroll
      for (int r = 0; r < 4; r++) pk.h4[r] = (_Float16)acc[mt][nt][r];
      *(uint2*)&e[((size_t)ch * 512 + h) * 128 + nn0] = pk.u;
    }
  }
}

// ---- fused layer tail: inv-row-DFT + conv MLP + v-residual (+ next row-DFT) ----
// One block per h row; 8 chunks of 64 w. LDS regions:
//   E[64][136]   : e rows for this h (K=128)                 (whole kernel)
//   P (18432 B)  : B4c[64][136] -> Vold f32[64][68] -> B1c[128][72]  (per chunk)
//   XpVn[64][72] : S^T[w][ch] (GEMM-A B-src) -> v_new f16 [ch][w] (GEMM-2 B-src)
//   Y1T[64][72]  : gelu1^T [w][o]
template <bool WRITE_T1>
__global__ __launch_bounds__(256) void k_tail(const _Float16* __restrict__ e,
                                              float* __restrict__ v,
                                              const _Float16* __restrict__ B4t,
                                              const _Float16* __restrict__ B1t,
                                              const float* __restrict__ w1,
                                              const float* __restrict__ b1,
                                              const float* __restrict__ w2,
                                              const float* __restrict__ b2,
                                              _Float16* __restrict__ t1) {
  __shared__ alignas(16) _Float16 E[64 * 136];
  __shared__ alignas(16) _Float16 P[128 * 72];
  __shared__ alignas(16) _Float16 XpVn[64 * 72];
  __shared__ alignas(16) _Float16 Y1T[64 * 72];
  __shared__ alignas(16) _Float16 W1h[64 * 72];
  __shared__ alignas(16) _Float16 W2h[64 * 72];
  __shared__ float B1s[64], B2s[64];
  int tid = threadIdx.x;
  int h = blockIdx.x;
  int wv = tid >> 6, lane = tid & 63;
  int col = lane & 15, quad = lane >> 4;
  int prow = 16 * wv + col;           // MLP/GEMM-0/GEMM-2 w-lane index (0..63)

  // one-time loads
  #pragma unroll
  for (int i = 0; i < 4; i++) {       // E[ch][k]
    int f = tid + 256 * i;
    int r_ = f >> 4, c8 = f & 15;
    *(half8*)&E[r_ * 136 + c8 * 8] =
        *(const half8*)&e[((size_t)r_ * 512 + h) * 128 + c8 * 8];
  }
  for (int j = tid; j < 4096; j += 256) {
    int a_ = j >> 6, b_ = j & 63;
    W1h[a_ * 72 + b_] = (_Float16)w1[j];
    W2h[a_ * 72 + b_] = (_Float16)w2[j];
  }
  if (tid < 64) { B1s[tid] = b1[tid]; B2s[tid] = b2[tid]; }

  f32x4 acc2[2][4];                   // next-layer t1 accumulators
  #pragma unroll
  for (int mt = 0; mt < 2; mt++)
    #pragma unroll
    for (int nt = 0; nt < 4; nt++) acc2[mt][nt] = (f32x4){0.f, 0.f, 0.f, 0.f};

  for (int wc = 0; wc < 8; wc++) {
    int w0 = wc * 64;
    __syncthreads();                  // B0: prev-chunk P readers done (also covers one-time loads)
    // S1: stage B4c -> P  ([64 w][136] rows of B4T[w][k])
    #pragma unroll
    for (int i = 0; i < 4; i++) {
      int f = tid + 256 * i;
      int r_ = f >> 4, c8 = f & 15;
      *(half8*)&P[r_ * 136 + c8 * 8] =
          *(const half8*)&B4t[(size_t)(w0 + r_) * 128 + c8 * 8];
    }
    __syncthreads();                  // B1
    // S2: GEMM-0  S[ch][w] = E x B4c^T  (M=ch 64, N=w 64, K=128)
    {
      f32x4 a0[4];
      #pragma unroll
      for (int nt = 0; nt < 4; nt++) a0[nt] = (f32x4){0.f, 0.f, 0.f, 0.f};
      #pragma unroll
      for (int ks = 0; ks < 4; ks++) {
        half8 af = *(const half8*)&E[(16 * wv + col) * 136 + ks * 32 + quad * 8];
        #pragma unroll
        for (int nt = 0; nt < 4; nt++) {
          half8 bf = *(const half8*)&P[(16 * nt + col) * 136 + ks * 32 + quad * 8];
          a0[nt] = __builtin_amdgcn_mfma_f32_16x16x32_f16(af, bf, a0[nt], 0, 0, 0);
        }
      }
      // epilogue-0: Xp[w][ch] (packed 8B; ch-nibble = this wave's 16wv+quad*4)
      #pragma unroll
      for (int nt = 0; nt < 4; nt++) {
        union { _Float16 h4[4]; uint2 u; } pk;
        #pragma unroll
        for (int r = 0; r < 4; r++) pk.h4[r] = (_Float16)a0[nt][r];
        *(uint2*)&XpVn[(16 * nt + col) * 72 + 16 * wv + quad * 4] = pk.u;
      }
    }
    __syncthreads();                  // B2: Xp ready; B4c dead
    // S3: stage Vold -> P (f32 [64][68]) ; GEMM-A
    float* Vold = (float*)P;
    #pragma unroll
    for (int i = 0; i < 4; i++) {
      int f = tid + 256 * i;
      int r_ = f >> 4, c4 = f & 15;
      *(f32x4*)&Vold[r_ * 68 + c4 * 4] =
          *(const f32x4*)&v[(size_t)r_ * HWn + h * 512 + w0 + c4 * 4];
    }
    f32x4 a1[4];
    #pragma unroll
    for (int ot = 0; ot < 4; ot++) a1[ot] = (f32x4){0.f, 0.f, 0.f, 0.f};
    {
      half8 bfr[2];
      #pragma unroll
      for (int kh = 0; kh < 2; kh++)
        bfr[kh] = *(const half8*)&XpVn[prow * 72 + kh * 32 + quad * 8];
      #pragma unroll
      for (int ot = 0; ot < 4; ot++) {
        #pragma unroll
        for (int kh = 0; kh < 2; kh++) {
          half8 afr = *(const half8*)&W1h[(ot * 16 + col) * 72 + kh * 32 + quad * 8];
          a1[ot] = __builtin_amdgcn_mfma_f32_16x16x32_f16(afr, bfr[kh], a1[ot], 0, 0, 0);
        }
      }
      #pragma unroll
      for (int ot = 0; ot < 4; ot++) {
        int o0 = ot * 16 + quad * 4;
        union { _Float16 h4[4]; uint2 u; } pk;
        #pragma unroll
        for (int r = 0; r < 4; r++)
          pk.h4[r] = (_Float16)gelu_f(a1[ot][r] + B1s[o0 + r]);
        *(uint2*)&Y1T[prow * 72 + o0] = pk.u;
      }
    }
    __syncthreads();                  // B3: Y1T + Vold ready; Xp dead
    // S4: GEMM-B + epilogue (v_new)
    {
      f32x4 a2[4];
      #pragma unroll
      for (int ot = 0; ot < 4; ot++) a2[ot] = (f32x4){0.f, 0.f, 0.f, 0.f};
      half8 bfr[2];
      #pragma unroll
      for (int kh = 0; kh < 2; kh++)
        bfr[kh] = *(const half8*)&Y1T[prow * 72 + kh * 32 + quad * 8];
      #pragma unroll
      for (int ot = 0; ot < 4; ot++) {
        #pragma unroll
        for (int kh = 0; kh < 2; kh++) {
          half8 afr = *(const half8*)&W2h[(ot * 16 + col) * 72 + kh * 32 + quad * 8];
          a2[ot] = __builtin_amdgcn_mfma_f32_16x16x32_f16(afr, bfr[kh], a2[ot], 0, 0, 0);
        }
      }
      #pragma unroll
      for (int ot = 0; ot < 4; ot++) {
        #pragma unroll
        for (int r = 0; r < 4; r++) {
          int ch = ot * 16 + quad * 4 + r;
          float vo = Vold[ch * 68 + prow];
          float vn = vo + gelu_f(a2[ot][r] + B2s[ch]);
          v[(size_t)ch * HWn + h * 512 + w0 + prow] = vn;   // full-line per quad
          XpVn[ch * 72 + prow] = (_Float16)vn;              // Vn[ch][w]
        }
      }
    }
    __syncthreads();                  // B4: Vn ready; Vold dead
    if (WRITE_T1) {
      // S5a: stage B1c -> P ([128 n'][72] rows of B1t[n'][w-chunk])
      #pragma unroll
      for (int i = 0; i < 4; i++) {
        int f = tid + 256 * i;
        int r_ = f >> 3, c8 = f & 7;
        *(half8*)&P[r_ * 72 + c8 * 8] =
            *(const half8*)&B1t[(size_t)r_ * 512 + w0 + c8 * 8];
      }
      __syncthreads();                // B5
      // S5b: GEMM-2  acc2[n'][ch] += B1c x Vn^T  (M=n' 128, N=ch 64, K=64)
      #pragma unroll
      for (int mt = 0; mt < 2; mt++)
        #pragma unroll
        for (int kh = 0; kh < 2; kh++) {
          half8 af = *(const half8*)&P[(32 * wv + 16 * mt + col) * 72 + kh * 32 + quad * 8];
          #pragma unroll
          for (int nt = 0; nt < 4; nt++) {
            half8 bf = *(const half8*)&XpVn[(16 * nt + col) * 72 + kh * 32 + quad * 8];
            acc2[mt][nt] = __builtin_amdgcn_mfma_f32_16x16x32_f16(af, bf, acc2[mt][nt], 0, 0, 0);
          }
        }
    }
  }
  if (WRITE_T1) {
    // D[n'][ch] -> t1[h][ch][n'0..3] packed 8B (waves/mt/quad cover n' 0..127)
    #pragma unroll
    for (int mt = 0; mt < 2; mt++) {
      int n0 = 32 * wv + 16 * mt + quad * 4;
      #pragma unroll
      for (int nt = 0; nt < 4; nt++) {
        int ch = 16 * nt + col;
        union { _Float16 h4[4]; uint2 u; } pk;
        #pragma unroll
        for (int r = 0; r < 4; r++) pk.h4[r] = (_Float16)acc2[mt][nt][r];
        *(uint2*)&t1[((size_t)h * 64 + ch) * 128 + n0] = pk.u;
      }
    }
  }
}

__global__ __launch_bounds__(256) void k_decode(const float* __restrict__ v,
                                                const float* __restrict__ dw,
                                                const float* __restrict__ db,
                                                float* __restrict__ out) {
  __shared__ float wsm[64];
  int tid = threadIdx.x;
  if (tid < 64) wsm[tid] = dw[tid];
  __syncthreads();
  int p = blockIdx.x * 256 + tid;
  float acc = db[0];
  #pragma unroll
  for (int i = 0; i < 64; i++) acc = fmaf(wsm[i], v[i * HWn + p], acc);
  out[p] = acc;
}

extern "C" void kernel_launch(void* const* d_in, const int* in_sizes, int n_in,
                              void* d_out, int out_size, void* d_ws, size_t ws_size,
                              hipStream_t stream) {
  const float* u     = (const float*)d_in[0];
  const float* x     = (const float*)d_in[1];
  const float* enc_w = (const float*)d_in[2];
  const float* enc_b = (const float*)d_in[3];
  const float* dec_w = (const float*)d_in[4];
  const float* dec_b = (const float*)d_in[5];
  const float* c1w   = (const float*)d_in[6];
  const float* c1b   = (const float*)d_in[7];
  const float* c2w   = (const float*)d_in[8];
  const float* c2b   = (const float*)d_in[9];
  const float* Are   = (const float*)d_in[10];
  const float* Aim   = (const float*)d_in[11];
  float* out = (float*)d_out;
  float* ws = (float*)d_ws;

  _Float16* B1t = (_Float16*)ws;            // [128][512]
  _Float16* A2t = B1t + 65536;              // [128][512]
  _Float16* A3t = A2t + 65536;              // [512][128]
  _Float16* B4t = A3t + 65536;              // [512][128]
  float* v = ws + 131072;                   // [C][H][W] f32
  _Float16* t1 = (_Float16*)(v + (size_t)Cn * HWn);       // [H][C][128] f16
  _Float16* e  = t1 + (size_t)Hn * Cn * 128;              // [C][H][128] f16
  float2* cbuf = (float2*)(e + (size_t)Cn * Hn * 128);    // [C][M][M]
  float2* cmix = cbuf + (size_t)Cn * Mn * Mn;             // [C][M][M]

  k_init_tw<<<dim3(256), dim3(256), 0, stream>>>(B1t, A2t, A3t, B4t);
  k_encode<<<dim3(HWn / 256), dim3(256), 0, stream>>>(u, x, enc_w, enc_b, v);
  k_fwd1<<<dim3(Cn * Hn / 64), dim3(256), 0, stream>>>(v, B1t, t1);

  for (int l = 0; l < Ln; l++) {
    k_fwd2<<<dim3(Cn), dim3(256), 0, stream>>>(t1, A2t, cbuf);
    k_mix<<<dim3(Mn, 16), dim3(256), 0, stream>>>(
        Are + (size_t)l * Cn * Cn * Mn * Mn, Aim + (size_t)l * Cn * Cn * Mn * Mn,
        cbuf, cmix);
    k_inv1<<<dim3(Cn, 8), dim3(256), 0, stream>>>(cmix, A3t, e);
    if (l < Ln - 1) {
      k_tail<true><<<dim3(Hn), dim3(256), 0, stream>>>(
          e, v, B4t, B1t, c1w + (size_t)l * 4096, c1b + (size_t)l * 64,
          c2w + (size_t)l * 4096, c2b + (size_t)l * 64, t1);
    } else {
      k_tail<false><<<dim3(Hn), dim3(256), 0, stream>>>(
          e, v, B4t, B1t, c1w + (size_t)l * 4096, c1b + (size_t)l * 64,
          c2w + (size_t)l * 4096, c2b + (size_t)l * 64, t1);
    }
  }

  k_decode<<<dim3(HWn / 256), dim3(256), 0, stream>>>(v, dec_w, dec_b, out);

  (void)in_sizes; (void)n_in; (void)out_size; (void)ws_size;
}